// Round 1
// baseline (4707.406 us; speedup 1.0000x reference)
//
#include <hip/hip_runtime.h>

#define BB 2
#define SS 2048
#define DM 1024
#define NH 16
#define NKV 4
#define HD 64
#define NREP 4

// ---------------- Kernel 1: fused QKV projection + RoPE ----------------
// One block per token (b,s). x row staged in LDS, 256 threads x 6 outputs.
__global__ __launch_bounds__(256) void qkv_rope_kernel(
    const float* __restrict__ x, const float* __restrict__ cos_t, const float* __restrict__ sin_t,
    const float* __restrict__ Wq, const float* __restrict__ Wk, const float* __restrict__ Wv,
    float* __restrict__ qo, float* __restrict__ ko, float* __restrict__ vo)
{
    __shared__ float xs[DM];
    __shared__ float outs[1536];
    const int token = blockIdx.x;
    const int b = token / SS, s = token % SS;
    const int tid = threadIdx.x;

    const float* xrow = x + (size_t)token * DM;
    for (int i = tid; i < DM; i += 256) xs[i] = xrow[i];
    __syncthreads();

    #pragma unroll
    for (int j = 0; j < 6; ++j) {
        const int o = tid + j * 256;
        const float* W; int col, ncol;
        if (j < 4)       { W = Wq; col = o;        ncol = 1024; }
        else if (j == 4) { W = Wk; col = o - 1024; ncol = 256;  }
        else             { W = Wv; col = o - 1280; ncol = 256;  }
        const float* wp = W + col;
        float acc = 0.f;
        #pragma unroll 8
        for (int d = 0; d < DM; ++d) acc += xs[d] * wp[(size_t)d * ncol];
        outs[o] = acc;
    }
    __syncthreads();

    const float* crow = cos_t + (size_t)s * HD;
    const float* srow = sin_t + (size_t)s * HD;
    #pragma unroll
    for (int j = 0; j < 6; ++j) {
        const int o = tid + j * 256;
        const int d = o & 63;
        if (j < 4) {
            const int h = o >> 6;
            const float v0 = outs[o];
            const float pair = (d < 32) ? -outs[o + 32] : outs[o - 32];
            const float r = v0 * crow[d] + pair * srow[d];
            qo[(((size_t)b * NH + h) * SS + s) * HD + d] = r;
        } else if (j == 4) {
            const int kh = (o - 1024) >> 6;
            const float v0 = outs[o];
            const float pair = (d < 32) ? -outs[o + 32] : outs[o - 32];
            const float r = v0 * crow[d] + pair * srow[d];
            ko[(((size_t)b * NKV + kh) * SS + s) * HD + d] = r;
        } else {
            const int kh = (o - 1280) >> 6;
            vo[(((size_t)b * NKV + kh) * SS + s) * HD + d] = outs[o];
        }
    }
}

// ---------------- Kernel 2: causal GQA attention, one block per query row ----------------
__global__ __launch_bounds__(256) void attn_kernel(
    const float* __restrict__ q, const float* __restrict__ k, const float* __restrict__ v,
    float* __restrict__ out)
{
    __shared__ float qs[HD];
    __shared__ float sc[SS];
    __shared__ float red[256];

    const int idx = blockIdx.x;
    const int s = idx % SS;
    const int h = (idx / SS) % NH;
    const int b = idx / (SS * NH);
    const int kvh = h / NREP;
    const int tid = threadIdx.x;

    const size_t qbase = (((size_t)b * NH + h) * SS + s) * HD;
    const size_t kbase = ((size_t)b * NKV + kvh) * (size_t)SS * HD;

    if (tid < HD) qs[tid] = q[qbase + tid];
    __syncthreads();

    const int nk = s + 1;
    const float4* q4 = (const float4*)qs;

    // scores + running max
    float lmax = -1e30f;
    for (int j = tid; j < nk; j += 256) {
        const float4* krow = (const float4*)(k + kbase + (size_t)j * HD);
        float acc = 0.f;
        #pragma unroll
        for (int t = 0; t < 16; ++t) {
            const float4 a = q4[t], bk = krow[t];
            acc += a.x * bk.x + a.y * bk.y + a.z * bk.z + a.w * bk.w;
        }
        acc *= 0.125f;  // 1/sqrt(64)
        sc[j] = acc;
        lmax = fmaxf(lmax, acc);
    }
    red[tid] = lmax;
    __syncthreads();
    for (int off = 128; off > 0; off >>= 1) {
        if (tid < off) red[tid] = fmaxf(red[tid], red[tid + off]);
        __syncthreads();
    }
    const float m = red[0];
    __syncthreads();

    // exp + sum
    float lsum = 0.f;
    for (int j = tid; j < nk; j += 256) {
        const float p = __expf(sc[j] - m);
        sc[j] = p;
        lsum += p;
    }
    red[tid] = lsum;
    __syncthreads();
    for (int off = 128; off > 0; off >>= 1) {
        if (tid < off) red[tid] += red[tid + off];
        __syncthreads();
    }
    const float inv = 1.f / red[0];
    __syncthreads();

    // P @ V, 4-way split over keys, coalesced in d
    const int d = tid & 63, part = tid >> 6;
    float acc = 0.f;
    for (int j = part; j < nk; j += 4)
        acc += sc[j] * v[kbase + (size_t)j * HD + d];
    red[tid] = acc;
    __syncthreads();
    if (tid < 64) {
        const float o = (red[tid] + red[64 + tid] + red[128 + tid] + red[192 + tid]) * inv;
        out[(((size_t)b * SS + s) * NH + h) * HD + tid] = o;
    }
}

// ---------------- Kernel 3: output projection ----------------
__global__ __launch_bounds__(256) void out_proj_kernel(
    const float* __restrict__ a, const float* __restrict__ Wo, float* __restrict__ out)
{
    __shared__ float as[DM];
    const int token = blockIdx.x;
    const int tid = threadIdx.x;

    const float* arow = a + (size_t)token * DM;
    for (int i = tid; i < DM; i += 256) as[i] = arow[i];
    __syncthreads();

    #pragma unroll
    for (int j = 0; j < 4; ++j) {
        const int o = tid + j * 256;
        const float* wp = Wo + o;
        float acc = 0.f;
        #pragma unroll 8
        for (int d = 0; d < DM; ++d) acc += as[d] * wp[(size_t)d * DM];
        out[(size_t)token * DM + o] = acc;
    }
}

extern "C" void kernel_launch(void* const* d_in, const int* in_sizes, int n_in,
                              void* d_out, int out_size, void* d_ws, size_t ws_size,
                              hipStream_t stream) {
    const float* x     = (const float*)d_in[0];
    const float* cos_t = (const float*)d_in[1];
    const float* sin_t = (const float*)d_in[2];
    const float* Wq    = (const float*)d_in[3];
    const float* Wk    = (const float*)d_in[4];
    const float* Wv    = (const float*)d_in[5];
    const float* Wo    = (const float*)d_in[6];
    float* out = (float*)d_out;

    // workspace layout (floats)
    float* ws = (float*)d_ws;
    float* q      = ws;                              // B*H*S*HD  = 4,194,304
    float* kk     = q + (size_t)BB * NH * SS * HD;   // B*KV*S*HD = 1,048,576
    float* vv     = kk + (size_t)BB * NKV * SS * HD; // 1,048,576
    float* attn_o = vv + (size_t)BB * NKV * SS * HD; // B*S*H*HD  = 4,194,304

    qkv_rope_kernel<<<BB * SS, 256, 0, stream>>>(x, cos_t, sin_t, Wq, Wk, Wv, q, kk, vv);
    attn_kernel<<<BB * NH * SS, 256, 0, stream>>>(q, kk, vv, attn_o);
    out_proj_kernel<<<BB * SS, 256, 0, stream>>>(attn_o, Wo, out);
}

// Round 2
// 293.602 us; speedup vs baseline: 16.0333x; 16.0333x over previous
//
#include <hip/hip_runtime.h>

#define BB 2
#define SS 2048
#define DM 1024
#define NH 16
#define NKV 4
#define HD 64

typedef __bf16 bf16;
typedef __bf16 bf16x8 __attribute__((ext_vector_type(8)));
typedef float f32x4 __attribute__((ext_vector_type(4)));

// ---------------- convert x: fp32 -> bf16 ----------------
__global__ __launch_bounds__(256) void convert_x_kernel(const float* __restrict__ x, bf16* __restrict__ xb)
{
    const int i = blockIdx.x * 256 + threadIdx.x;
    const float4 v = ((const float4*)x)[i];
    bf16* o = xb + (size_t)i * 4;
    o[0] = (bf16)v.x; o[1] = (bf16)v.y; o[2] = (bf16)v.z; o[3] = (bf16)v.w;
}

// ---------------- weight transpose + convert: W(K,N) fp32 -> Wt(N,K=1024) bf16 ----------------
__global__ __launch_bounds__(256) void transpose_to_bf16(const float* __restrict__ W, bf16* __restrict__ Wt, int N)
{
    __shared__ float Ts[64][65];
    const int n0 = blockIdx.x * 64, k0 = blockIdx.y * 64;
    const int tid = threadIdx.x;
    const int c = tid & 63, rr = tid >> 6;
    #pragma unroll
    for (int i = 0; i < 16; ++i) {
        const int kk = i * 4 + rr;
        Ts[kk][c] = W[(size_t)(k0 + kk) * N + n0 + c];
    }
    __syncthreads();
    #pragma unroll
    for (int i = 0; i < 16; ++i) {
        const int nn = i * 4 + rr;
        Wt[(size_t)(n0 + nn) * 1024 + k0 + c] = (bf16)Ts[c][nn];
    }
}

// ---------------- bf16 MFMA GEMM: A(M,K) row-major, Bt(N,K) row-major, C(M,N) ----------------
// 128x128 tile, BK=32, 256 threads = 4 waves (2x2 of 64x64), 16x16x32 MFMA.
template<bool OUT_BF16>
__global__ __launch_bounds__(256) void gemm_bt_kernel(const bf16* __restrict__ A, const bf16* __restrict__ Bt,
                                                      void* __restrict__ Cv, int M, int N, int K)
{
    __shared__ bf16 As[128][40];
    __shared__ bf16 Bs[128][40];
    const int m0 = blockIdx.x * 128, n0 = blockIdx.y * 128;
    const int tid = threadIdx.x;
    const int w = tid >> 6, lane = tid & 63, g = lane >> 4, li = lane & 15;
    const int wm = w & 1, wn = w >> 1;
    const int srow = tid >> 1, shalf = tid & 1;

    f32x4 acc[4][4];
    const f32x4 z = {0.f, 0.f, 0.f, 0.f};
    #pragma unroll
    for (int i = 0; i < 4; ++i)
        #pragma unroll
        for (int j = 0; j < 4; ++j) acc[i][j] = z;

    const bf16* aptr = A + (size_t)(m0 + srow) * K + shalf * 16;
    const bf16* bptr = Bt + (size_t)(n0 + srow) * K + shalf * 16;

    for (int kk = 0; kk < K; kk += 32) {
        __syncthreads();
        {
            const uint4* a4 = (const uint4*)(aptr + kk);
            const uint4 v0 = a4[0], v1 = a4[1];
            *(uint4*)&As[srow][shalf * 16] = v0;
            *(uint4*)&As[srow][shalf * 16 + 8] = v1;
            const uint4* b4 = (const uint4*)(bptr + kk);
            const uint4 u0 = b4[0], u1 = b4[1];
            *(uint4*)&Bs[srow][shalf * 16] = u0;
            *(uint4*)&Bs[srow][shalf * 16 + 8] = u1;
        }
        __syncthreads();
        bf16x8 af[4], bfr[4];
        #pragma unroll
        for (int mi = 0; mi < 4; ++mi) af[mi] = *(const bf16x8*)&As[wm * 64 + mi * 16 + li][g * 8];
        #pragma unroll
        for (int ni = 0; ni < 4; ++ni) bfr[ni] = *(const bf16x8*)&Bs[wn * 64 + ni * 16 + li][g * 8];
        #pragma unroll
        for (int mi = 0; mi < 4; ++mi)
            #pragma unroll
            for (int ni = 0; ni < 4; ++ni)
                acc[mi][ni] = __builtin_amdgcn_mfma_f32_16x16x32_bf16(af[mi], bfr[ni], acc[mi][ni], 0, 0, 0);
    }

    const int row0 = m0 + wm * 64, col0 = n0 + wn * 64;
    #pragma unroll
    for (int mi = 0; mi < 4; ++mi)
        #pragma unroll
        for (int ni = 0; ni < 4; ++ni)
            #pragma unroll
            for (int r = 0; r < 4; ++r) {
                const int row = row0 + mi * 16 + g * 4 + r;
                const int col = col0 + ni * 16 + li;
                if (OUT_BF16) ((bf16*)Cv)[(size_t)row * N + col] = (bf16)acc[mi][ni][r];
                else          ((float*)Cv)[(size_t)row * N + col] = acc[mi][ni][r];
            }
}

// ---------------- RoPE + split into (b,h,s,d) bf16 layouts ----------------
__global__ __launch_bounds__(256) void rope_split_kernel(const bf16* __restrict__ qkv,
                                                         const float* __restrict__ cos_t, const float* __restrict__ sin_t,
                                                         bf16* __restrict__ q, bf16* __restrict__ k, bf16* __restrict__ v)
{
    __shared__ float ls[1536];
    const int token = blockIdx.x;
    const int b = token >> 11, s = token & 2047;
    const int tid = threadIdx.x;
    const bf16* row = qkv + (size_t)token * 1536;
    #pragma unroll
    for (int j = 0; j < 6; ++j) ls[tid + j * 256] = (float)row[tid + j * 256];
    __syncthreads();
    const float* crow = cos_t + (size_t)s * HD;
    const float* srow = sin_t + (size_t)s * HD;
    #pragma unroll
    for (int j = 0; j < 6; ++j) {
        const int o = tid + j * 256;
        const int d = o & 63;
        if (o < 1024) {
            const int h = o >> 6;
            const float pair = (d < 32) ? -ls[o + 32] : ls[o - 32];
            const float r = ls[o] * crow[d] + pair * srow[d];
            q[(((size_t)b * NH + h) * SS + s) * HD + d] = (bf16)r;
        } else if (o < 1280) {
            const int kh = (o - 1024) >> 6;
            const float pair = (d < 32) ? -ls[o + 32] : ls[o - 32];
            const float r = ls[o] * crow[d] + pair * srow[d];
            k[(((size_t)b * NKV + kh) * SS + s) * HD + d] = (bf16)r;
        } else {
            const int kh = (o - 1280) >> 6;
            v[(((size_t)b * NKV + kh) * SS + s) * HD + d] = (bf16)ls[o];
        }
    }
}

// ---------------- Flash attention, bf16 MFMA ----------------
// Block = 64-row Q-tile of one (b,h). 4 waves, wave w owns q-rows [w*16, w*16+16).
// C/D layout (verified): col = lane&15, row = (lane>>4)*4 + reg.
// A layout (verified): A[m = lane&15][k = (lane>>4)*8 + j].
#define FL_PAD 72
__global__ __launch_bounds__(256) void flash_kernel(const bf16* __restrict__ q, const bf16* __restrict__ k,
                                                    const bf16* __restrict__ v, bf16* __restrict__ o)
{
    __shared__ bf16 Qs[64][FL_PAD];
    __shared__ bf16 Ks[64][FL_PAD];
    __shared__ bf16 Vt[64][FL_PAD];
    __shared__ bf16 Ps[4][16][FL_PAD];

    const int blk = blockIdx.x;
    const int qt = 31 - (blk & 31);          // heavy diagonal tiles first
    const int h = (blk >> 5) & 15;
    const int b = blk >> 9;
    const int kvh = h >> 2;
    const int tid = threadIdx.x;
    const int w = tid >> 6, lane = tid & 63, g = lane >> 4, li = lane & 15;

    const bf16* qbase = q + (((size_t)b * NH + h) * SS + qt * 64) * HD;
    const bf16* kbase = k + (((size_t)b * NKV + kvh) * SS) * HD;
    const bf16* vbase = v + (((size_t)b * NKV + kvh) * SS) * HD;

    {   // stage Q tile (64x64)
        const int row = tid >> 2, qu = tid & 3;
        const uint4* src = (const uint4*)(qbase + row * 64 + qu * 16);
        const uint4 v0 = src[0], v1 = src[1];
        *(uint4*)&Qs[row][qu * 16] = v0;
        *(uint4*)&Qs[row][qu * 16 + 8] = v1;
    }
    __syncthreads();

    bf16x8 qf[2];
    qf[0] = *(const bf16x8*)&Qs[w * 16 + li][g * 8];
    qf[1] = *(const bf16x8*)&Qs[w * 16 + li][32 + g * 8];

    const f32x4 z = {0.f, 0.f, 0.f, 0.f};
    f32x4 o_acc[4];
    float m_i[4], l_i[4];
    #pragma unroll
    for (int r = 0; r < 4; ++r) { o_acc[r] = z; m_i[r] = -3e38f; l_i[r] = 0.f; }

    for (int kt = 0; kt <= qt; ++kt) {
        __syncthreads();
        {   // stage K tile + V tile (transposed)
            const int row = tid >> 2, qu = tid & 3;
            const uint4* ksrc = (const uint4*)(kbase + ((size_t)kt * 64 + row) * 64 + qu * 16);
            const uint4 v0 = ksrc[0], v1 = ksrc[1];
            *(uint4*)&Ks[row][qu * 16] = v0;
            *(uint4*)&Ks[row][qu * 16 + 8] = v1;
            const bf16* vsrc = vbase + ((size_t)kt * 64 + row) * 64 + qu * 16;
            bf16 tmp[16];
            *(uint4*)&tmp[0] = *(const uint4*)vsrc;
            *(uint4*)&tmp[8] = *(const uint4*)(vsrc + 8);
            #pragma unroll
            for (int e = 0; e < 16; ++e) Vt[qu * 16 + e][row] = tmp[e];
        }
        __syncthreads();

        // S = Q @ K^T   (16 q-rows x 64 keys per wave)
        f32x4 s_acc[4];
        #pragma unroll
        for (int nt = 0; nt < 4; ++nt) s_acc[nt] = z;
        #pragma unroll
        for (int nt = 0; nt < 4; ++nt)
            #pragma unroll
            for (int t = 0; t < 2; ++t) {
                const bf16x8 kf = *(const bf16x8*)&Ks[nt * 16 + li][t * 32 + g * 8];
                s_acc[nt] = __builtin_amdgcn_mfma_f32_16x16x32_bf16(qf[t], kf, s_acc[nt], 0, 0, 0);
            }

        // scale + causal mask on diagonal tile
        const bool diag = (kt == qt);
        const int qrow_abs = qt * 64 + w * 16 + g * 4;
        #pragma unroll
        for (int nt = 0; nt < 4; ++nt) {
            const int key_abs = kt * 64 + nt * 16 + li;
            #pragma unroll
            for (int r = 0; r < 4; ++r) {
                float sv = s_acc[nt][r] * 0.125f;
                if (diag && key_abs > qrow_abs + r) sv = -3e38f;
                s_acc[nt][r] = sv;
            }
        }

        // online softmax (per q-row; 16 lanes of a group hold the 16 cols)
        float alpha[4];
        #pragma unroll
        for (int r = 0; r < 4; ++r) {
            float vm = fmaxf(fmaxf(s_acc[0][r], s_acc[1][r]), fmaxf(s_acc[2][r], s_acc[3][r]));
            vm = fmaxf(vm, __shfl_xor(vm, 1));
            vm = fmaxf(vm, __shfl_xor(vm, 2));
            vm = fmaxf(vm, __shfl_xor(vm, 4));
            vm = fmaxf(vm, __shfl_xor(vm, 8));
            const float mn = fmaxf(m_i[r], vm);
            alpha[r] = __expf(m_i[r] - mn);
            m_i[r] = mn;
        }
        #pragma unroll
        for (int r = 0; r < 4; ++r) {
            float rs = 0.f;
            #pragma unroll
            for (int nt = 0; nt < 4; ++nt) {
                const float p = __expf(s_acc[nt][r] - m_i[r]);
                Ps[w][g * 4 + r][nt * 16 + li] = (bf16)p;
                rs += p;
            }
            rs += __shfl_xor(rs, 1);
            rs += __shfl_xor(rs, 2);
            rs += __shfl_xor(rs, 4);
            rs += __shfl_xor(rs, 8);
            l_i[r] = l_i[r] * alpha[r] + rs;
            #pragma unroll
            for (int nt = 0; nt < 4; ++nt) o_acc[nt][r] *= alpha[r];
        }

        // O += P @ V  (P: A-layout from LDS round-trip; Vt: B-layout, d-major)
        #pragma unroll
        for (int t = 0; t < 2; ++t) {
            const bf16x8 pf = *(const bf16x8*)&Ps[w][li][t * 32 + g * 8];
            #pragma unroll
            for (int nt = 0; nt < 4; ++nt) {
                const bf16x8 vf = *(const bf16x8*)&Vt[nt * 16 + li][t * 32 + g * 8];
                o_acc[nt] = __builtin_amdgcn_mfma_f32_16x16x32_bf16(pf, vf, o_acc[nt], 0, 0, 0);
            }
        }
    }

    // epilogue: O / l, write (b, s, h, d) bf16
    const int s_abs = qt * 64 + w * 16 + g * 4;
    #pragma unroll
    for (int r = 0; r < 4; ++r) {
        const float inv = 1.f / l_i[r];
        const int srow = s_abs + r;
        bf16* orow = o + (((size_t)b * SS + srow) * NH + h) * HD;
        #pragma unroll
        for (int nt = 0; nt < 4; ++nt) orow[nt * 16 + li] = (bf16)(o_acc[nt][r] * inv);
    }
}

extern "C" void kernel_launch(void* const* d_in, const int* in_sizes, int n_in,
                              void* d_out, int out_size, void* d_ws, size_t ws_size,
                              hipStream_t stream) {
    const float* x     = (const float*)d_in[0];
    const float* cos_t = (const float*)d_in[1];
    const float* sin_t = (const float*)d_in[2];
    const float* Wq    = (const float*)d_in[3];
    const float* Wk    = (const float*)d_in[4];
    const float* Wv    = (const float*)d_in[5];
    const float* Wo    = (const float*)d_in[6];
    float* out = (float*)d_out;

    char* wsb = (char*)d_ws;
    bf16* x_b    = (bf16*)(wsb);                 // 8,388,608 B (reused as o_b later)
    bf16* wqkv_t = (bf16*)(wsb + 8388608);       // 3,145,728 B  (1536 x 1024)
    bf16* wo_t   = (bf16*)(wsb + 11534336);      // 2,097,152 B  (1024 x 1024)
    bf16* qkv_b  = (bf16*)(wsb + 13631488);      // 12,582,912 B (4096 x 1536)
    bf16* q_b    = (bf16*)(wsb + 26214400);      // 8,388,608 B
    bf16* k_b    = (bf16*)(wsb + 34603008);      // 2,097,152 B
    bf16* v_b    = (bf16*)(wsb + 36700160);      // 2,097,152 B -> total 38,797,312 B
    bf16* o_b    = x_b;                          // alias: x_b dead after QKV GEMM

    convert_x_kernel<<<4096, 256, 0, stream>>>(x, x_b);
    transpose_to_bf16<<<dim3(16, 16), 256, 0, stream>>>(Wq, wqkv_t, 1024);
    transpose_to_bf16<<<dim3(4, 16), 256, 0, stream>>>(Wk, wqkv_t + (size_t)1024 * 1024, 256);
    transpose_to_bf16<<<dim3(4, 16), 256, 0, stream>>>(Wv, wqkv_t + (size_t)1280 * 1024, 256);
    transpose_to_bf16<<<dim3(16, 16), 256, 0, stream>>>(Wo, wo_t, 1024);

    gemm_bt_kernel<true><<<dim3(32, 12), 256, 0, stream>>>(x_b, wqkv_t, qkv_b, 4096, 1536, 1024);
    rope_split_kernel<<<4096, 256, 0, stream>>>(qkv_b, cos_t, sin_t, q_b, k_b, v_b);
    flash_kernel<<<1024, 256, 0, stream>>>(q_b, k_b, v_b, o_b);
    gemm_bt_kernel<false><<<dim3(32, 8), 256, 0, stream>>>(o_b, wo_t, out, 4096, 1024, 1024);
}

// Round 3
// 218.802 us; speedup vs baseline: 21.5144x; 1.3419x over previous
//
#include <hip/hip_runtime.h>

#define BB 2
#define SS 2048
#define DM 1024
#define NH 16
#define NKV 4
#define HD 64

typedef __bf16 bf16;
typedef __bf16 bf16x8 __attribute__((ext_vector_type(8)));
typedef float f32x4 __attribute__((ext_vector_type(4)));

// exp2-folded softmax scale: (1/sqrt(64)) * log2(e)
#define SM_SCALE 0.18033688011f

__device__ __forceinline__ void gl_lds16(const bf16* g, bf16* l) {
    __builtin_amdgcn_global_load_lds((const __attribute__((address_space(1))) void*)g,
                                     (__attribute__((address_space(3))) void*)l, 16, 0, 0);
}

// ---------------- convert x: fp32 -> bf16 ----------------
__global__ __launch_bounds__(256) void convert_x_kernel(const float* __restrict__ x, bf16* __restrict__ xb)
{
    const int i = blockIdx.x * 256 + threadIdx.x;
    const float4 v = ((const float4*)x)[i];
    bf16* o = xb + (size_t)i * 4;
    o[0] = (bf16)v.x; o[1] = (bf16)v.y; o[2] = (bf16)v.z; o[3] = (bf16)v.w;
}

// ---------------- weight transpose + convert: W(K,N) fp32 -> Wt(N,K=1024) bf16 ----------------
__global__ __launch_bounds__(256) void transpose_to_bf16(const float* __restrict__ W, bf16* __restrict__ Wt, int N)
{
    __shared__ float Ts[64][65];
    const int n0 = blockIdx.x * 64, k0 = blockIdx.y * 64;
    const int tid = threadIdx.x;
    const int c = tid & 63, rr = tid >> 6;
    #pragma unroll
    for (int i = 0; i < 16; ++i) {
        const int kk = i * 4 + rr;
        Ts[kk][c] = W[(size_t)(k0 + kk) * N + n0 + c];
    }
    __syncthreads();
    #pragma unroll
    for (int i = 0; i < 16; ++i) {
        const int nn = i * 4 + rr;
        Wt[(size_t)(n0 + nn) * 1024 + k0 + c] = (bf16)Ts[c][nn];
    }
}

// ---------------- bf16 MFMA GEMM with global_load_lds staging (m97 pattern) ----------------
// A(M,K) row-major bf16, Bt(N,K) row-major bf16. 128x128 tile, BK=32, 4 waves.
// EPI=0: C fp32 plain.  EPI=2: fused RoPE + QKV split epilogue (N=1536).
template<int EPI>
__global__ __launch_bounds__(256) void gemm_bt_kernel(
    const bf16* __restrict__ A, const bf16* __restrict__ Bt, float* __restrict__ C,
    const float* __restrict__ cosp, const float* __restrict__ sinp,
    bf16* __restrict__ qo, bf16* __restrict__ ko, bf16* __restrict__ vto,
    int M, int N, int K)
{
    __shared__ bf16 As[128 * 32];   // 8 KB, unpadded, row-major 128x32
    __shared__ bf16 Bs[128 * 32];
    const int m0 = blockIdx.x * 128, n0 = blockIdx.y * 128;
    const int tid = threadIdx.x;
    const int w = tid >> 6, lane = tid & 63, g = lane >> 4, li = lane & 15;
    const int wm = w & 1, wn = w >> 1;

    f32x4 acc[4][4];
    const f32x4 z = {0.f, 0.f, 0.f, 0.f};
    #pragma unroll
    for (int i = 0; i < 4; ++i)
        #pragma unroll
        for (int j = 0; j < 4; ++j) acc[i][j] = z;

    // staging: region r = w*2+i covers rows r*16..r*16+16 (16 rows x 64 B), lane l -> row r*16 + l/4, 16B-chunk l%4
    const int r0 = w * 2, r1 = w * 2 + 1;
    const int lrow = lane >> 2, kcol = (lane & 3) * 8;
    const bf16* pA0 = A + (size_t)(m0 + r0 * 16 + lrow) * K + kcol;
    const bf16* pA1 = A + (size_t)(m0 + r1 * 16 + lrow) * K + kcol;
    const bf16* pB0 = Bt + (size_t)(n0 + r0 * 16 + lrow) * K + kcol;
    const bf16* pB1 = Bt + (size_t)(n0 + r1 * 16 + lrow) * K + kcol;
    bf16* lA0 = As + r0 * 512;  bf16* lA1 = As + r1 * 512;
    bf16* lB0 = Bs + r0 * 512;  bf16* lB1 = Bs + r1 * 512;

    for (int kk = 0; kk < K; kk += 32) {
        __syncthreads();
        gl_lds16(pA0 + kk, lA0);
        gl_lds16(pA1 + kk, lA1);
        gl_lds16(pB0 + kk, lB0);
        gl_lds16(pB1 + kk, lB1);
        __syncthreads();
        bf16x8 af[4], bfr[4];
        #pragma unroll
        for (int mi = 0; mi < 4; ++mi) af[mi] = *(const bf16x8*)&As[(wm * 64 + mi * 16 + li) * 32 + g * 8];
        #pragma unroll
        for (int ni = 0; ni < 4; ++ni) bfr[ni] = *(const bf16x8*)&Bs[(wn * 64 + ni * 16 + li) * 32 + g * 8];
        #pragma unroll
        for (int mi = 0; mi < 4; ++mi)
            #pragma unroll
            for (int ni = 0; ni < 4; ++ni)
                acc[mi][ni] = __builtin_amdgcn_mfma_f32_16x16x32_bf16(af[mi], bfr[ni], acc[mi][ni], 0, 0, 0);
    }

    const int row0 = m0 + wm * 64, col0 = n0 + wn * 64;
    if (EPI == 0) {
        #pragma unroll
        for (int mi = 0; mi < 4; ++mi)
            #pragma unroll
            for (int ni = 0; ni < 4; ++ni)
                #pragma unroll
                for (int r = 0; r < 4; ++r)
                    C[(size_t)(row0 + mi * 16 + g * 4 + r) * N + col0 + ni * 16 + li] = acc[mi][ni][r];
    } else {
        // fused RoPE + split. cols: [0,1024) q, [1024,1280) k, [1280,1536) v.
        // rotate_half partner of col is col^32 == acc[mi][ni^2][r] (same wave, in-register).
        #pragma unroll
        for (int ni = 0; ni < 4; ++ni) {
            const int col = col0 + ni * 16 + li;
            const int d = col & 63;
            #pragma unroll
            for (int mi = 0; mi < 4; ++mi) {
                #pragma unroll
                for (int r = 0; r < 4; ++r) {
                    const int row = row0 + mi * 16 + g * 4 + r;
                    const int bb = row >> 11, s = row & 2047;
                    float val = acc[mi][ni][r];
                    if (col < 1280) {
                        const float pairv = acc[mi][ni ^ 2][r];
                        const float rot = (d < 32) ? -pairv : pairv;
                        val = val * cosp[s * 64 + d] + rot * sinp[s * 64 + d];
                    }
                    if (col < 1024) {
                        const int hh = col >> 6;
                        qo[(((size_t)bb * NH + hh) * SS + s) * HD + d] = (bf16)val;
                    } else if (col < 1280) {
                        const int kh = (col - 1024) >> 6;
                        ko[(((size_t)bb * NKV + kh) * SS + s) * HD + d] = (bf16)val;
                    } else {
                        const int kh = (col - 1280) >> 6;
                        vto[(((size_t)bb * NKV + kh) * HD + d) * SS + s] = (bf16)val;  // V^T: [d][s]
                    }
                }
            }
        }
    }
}

// ---------------- Flash attention v2: paired Q-tiles, no-max exp2 softmax, MFMA rowsum ----------------
// grid = B*NH*16 blocks; block processes Q-tiles qt=31-p and qt=p (balanced 33 steps).
// V is pre-transposed in global ([b][kvh][d][s]) -> conflict-free b128 staging.
#define FP 72
__global__ __launch_bounds__(256) void flash_kernel(const bf16* __restrict__ q, const bf16* __restrict__ k,
                                                    const bf16* __restrict__ vt, bf16* __restrict__ o)
{
    __shared__ bf16 Ks[64][FP];
    __shared__ bf16 Vt[64][FP];
    __shared__ bf16 Ps[4][16][FP];

    const int blk = blockIdx.x;
    const int p = blk & 15;
    const int h = (blk >> 4) & 15;
    const int b = blk >> 8;
    const int kvh = h >> 2;
    const int tid = threadIdx.x;
    const int w = tid >> 6, lane = tid & 63, g = lane >> 4, li = lane & 15;
    const int srow = tid >> 2, squ = tid & 3;

    const bf16* qh = q + ((size_t)b * NH + h) * SS * HD;
    const bf16* kh = k + ((size_t)b * NKV + kvh) * SS * HD;
    const bf16* vh = vt + ((size_t)b * NKV + kvh) * (size_t)HD * SS;

    bf16x8 ones;
    #pragma unroll
    for (int j = 0; j < 8; ++j) ones[j] = (bf16)1.0f;
    const f32x4 z = {0.f, 0.f, 0.f, 0.f};

    #pragma unroll
    for (int phase = 0; phase < 2; ++phase) {
        const int qt = phase ? p : (31 - p);

        // Q fragments straight from global (A-layout: row=li, k=g*8+j)
        const bf16* qrow = qh + (size_t)(qt * 64 + w * 16 + li) * HD;
        bf16x8 qf[2];
        qf[0] = *(const bf16x8*)(qrow + g * 8);
        qf[1] = *(const bf16x8*)(qrow + 32 + g * 8);

        f32x4 o_acc[4], l_acc;
        #pragma unroll
        for (int nt = 0; nt < 4; ++nt) o_acc[nt] = z;
        l_acc = z;

        for (int kt = 0; kt <= qt; ++kt) {
            __syncthreads();
            {   // stage K (rows=key) and V^T (rows=d) — both coalesced b128
                const uint4* ks = (const uint4*)(kh + (size_t)(kt * 64 + srow) * HD + squ * 16);
                const uint4 a0 = ks[0], a1 = ks[1];
                *(uint4*)&Ks[srow][squ * 16] = a0;
                *(uint4*)&Ks[srow][squ * 16 + 8] = a1;
                const uint4* vs = (const uint4*)(vh + (size_t)srow * SS + kt * 64 + squ * 16);
                const uint4 c0 = vs[0], c1 = vs[1];
                *(uint4*)&Vt[srow][squ * 16] = c0;
                *(uint4*)&Vt[srow][squ * 16 + 8] = c1;
            }
            __syncthreads();

            // S = Q @ K^T  (16 q-rows x 64 keys per wave)
            f32x4 s_acc[4];
            #pragma unroll
            for (int nt = 0; nt < 4; ++nt) s_acc[nt] = z;
            #pragma unroll
            for (int t = 0; t < 2; ++t)
                #pragma unroll
                for (int nt = 0; nt < 4; ++nt) {
                    const bf16x8 kf = *(const bf16x8*)&Ks[nt * 16 + li][t * 32 + g * 8];
                    s_acc[nt] = __builtin_amdgcn_mfma_f32_16x16x32_bf16(qf[t], kf, s_acc[nt], 0, 0, 0);
                }

            // scale (exp2-folded), causal mask on diagonal, exp2, P -> LDS (bf16)
            const bool diag = (kt == qt);
            const int qr0 = qt * 64 + w * 16 + g * 4;
            #pragma unroll
            for (int nt = 0; nt < 4; ++nt) {
                const int key = kt * 64 + nt * 16 + li;
                #pragma unroll
                for (int r = 0; r < 4; ++r) {
                    float sv = s_acc[nt][r] * SM_SCALE;
                    if (diag && key > qr0 + r) sv = -1e30f;
                    Ps[w][g * 4 + r][nt * 16 + li] = (bf16)exp2f(sv);
                }
            }
            // same-wave LDS round-trip (C-layout -> A-layout); no barrier needed

            // O += P @ V ; l += P @ 1 (rowsum via ones-MFMA, broadcast to all lanes)
            #pragma unroll
            for (int t = 0; t < 2; ++t) {
                const bf16x8 pf = *(const bf16x8*)&Ps[w][li][t * 32 + g * 8];
                l_acc = __builtin_amdgcn_mfma_f32_16x16x32_bf16(pf, ones, l_acc, 0, 0, 0);
                #pragma unroll
                for (int nt = 0; nt < 4; ++nt) {
                    const bf16x8 vf = *(const bf16x8*)&Vt[nt * 16 + li][t * 32 + g * 8];
                    o_acc[nt] = __builtin_amdgcn_mfma_f32_16x16x32_bf16(pf, vf, o_acc[nt], 0, 0, 0);
                }
            }
        }

        // epilogue: O / l -> (b, s, h, d) bf16
        #pragma unroll
        for (int r = 0; r < 4; ++r) {
            const float inv = 1.f / l_acc[r];
            const int s = qt * 64 + w * 16 + g * 4 + r;
            bf16* orow = o + (((size_t)b * SS + s) * NH + h) * HD;
            #pragma unroll
            for (int nt = 0; nt < 4; ++nt) orow[nt * 16 + li] = (bf16)(o_acc[nt][r] * inv);
        }
    }
}

extern "C" void kernel_launch(void* const* d_in, const int* in_sizes, int n_in,
                              void* d_out, int out_size, void* d_ws, size_t ws_size,
                              hipStream_t stream) {
    const float* x     = (const float*)d_in[0];
    const float* cos_t = (const float*)d_in[1];
    const float* sin_t = (const float*)d_in[2];
    const float* Wq    = (const float*)d_in[3];
    const float* Wk    = (const float*)d_in[4];
    const float* Wv    = (const float*)d_in[5];
    const float* Wo    = (const float*)d_in[6];
    float* out = (float*)d_out;

    char* wsb = (char*)d_ws;
    bf16* x_b    = (bf16*)(wsb);                 //  8,388,608 B (aliased as o_b after QKV GEMM)
    bf16* wqkv_t = (bf16*)(wsb + 8388608);       //  3,145,728 B (1536 x 1024)
    bf16* wo_t   = (bf16*)(wsb + 11534336);      //  2,097,152 B (1024 x 1024)
    bf16* q_b    = (bf16*)(wsb + 13631488);      //  8,388,608 B
    bf16* k_b    = (bf16*)(wsb + 22020096);      //  2,097,152 B
    bf16* vt_b   = (bf16*)(wsb + 24117248);      //  2,097,152 B -> total 26,214,400 B
    bf16* o_b    = x_b;

    convert_x_kernel<<<4096, 256, 0, stream>>>(x, x_b);
    transpose_to_bf16<<<dim3(16, 16), 256, 0, stream>>>(Wq, wqkv_t, 1024);
    transpose_to_bf16<<<dim3(4, 16), 256, 0, stream>>>(Wk, wqkv_t + (size_t)1024 * 1024, 256);
    transpose_to_bf16<<<dim3(4, 16), 256, 0, stream>>>(Wv, wqkv_t + (size_t)1280 * 1024, 256);
    transpose_to_bf16<<<dim3(16, 16), 256, 0, stream>>>(Wo, wo_t, 1024);

    // QKV GEMM with fused RoPE + split (writes q_b, k_b, vt_b directly)
    gemm_bt_kernel<2><<<dim3(32, 12), 256, 0, stream>>>(x_b, wqkv_t, nullptr, cos_t, sin_t,
                                                        q_b, k_b, vt_b, 4096, 1536, 1024);
    flash_kernel<<<512, 256, 0, stream>>>(q_b, k_b, vt_b, o_b);
    gemm_bt_kernel<0><<<dim3(32, 8), 256, 0, stream>>>(o_b, wo_t, out, nullptr, nullptr,
                                                       nullptr, nullptr, nullptr, 4096, 1024, 1024);
}

// Round 6
// 192.695 us; speedup vs baseline: 24.4293x; 1.1355x over previous
//
#include <hip/hip_runtime.h>

#define SS 2048
#define NH 16
#define NKV 4
#define HD 64

typedef __bf16 bf16;
typedef __bf16 bf16x8 __attribute__((ext_vector_type(8)));
typedef float f32x4 __attribute__((ext_vector_type(4)));

// exp2-folded softmax scale: (1/sqrt(64)) * log2(e)
#define SM_SCALE 0.18033688011f

__device__ __forceinline__ void gl_lds16(const bf16* g, bf16* l) {
    __builtin_amdgcn_global_load_lds((const __attribute__((address_space(1))) void*)g,
                                     (__attribute__((address_space(3))) void*)l, 16, 0, 0);
}

// ---------------- prep: convert x to bf16 + transpose/convert all weights ----------------
// blocks 0..255: Wq (16x16 64-tiles), 256..319: Wk, 320..383: Wv, 384..639: Wo,
// 640..1151: x fp32->bf16 (512 blocks x 256 thr x 8 float4 = 1,048,576 float4 = whole x).
__global__ __launch_bounds__(256) void prep_kernel(
    const float* __restrict__ x, const float* __restrict__ Wq, const float* __restrict__ Wk,
    const float* __restrict__ Wv, const float* __restrict__ Wo,
    bf16* __restrict__ xb, bf16* __restrict__ wqkv_t, bf16* __restrict__ wo_t)
{
    const int blk = blockIdx.x;
    const int tid = threadIdx.x;
    if (blk >= 640) {
        const float4* xv = (const float4*)x;
        const size_t base = (size_t)(blk - 640) * 2048 + tid;   // float4 units
        #pragma unroll
        for (int j = 0; j < 8; ++j) {
            const float4 v = xv[base + j * 256];
            bf16* o = xb + (base + j * 256) * 4;
            o[0] = (bf16)v.x; o[1] = (bf16)v.y; o[2] = (bf16)v.z; o[3] = (bf16)v.w;
        }
        return;
    }
    const float* W; bf16* Wt; int N, n0, k0;
    if (blk < 256)      { W = Wq; Wt = wqkv_t;                       N = 1024; n0 = (blk & 15) * 64;         k0 = (blk >> 4) * 64; }
    else if (blk < 320) { W = Wk; Wt = wqkv_t + (size_t)1024 * 1024; N = 256;  n0 = ((blk - 256) & 3) * 64;  k0 = ((blk - 256) >> 2) * 64; }
    else if (blk < 384) { W = Wv; Wt = wqkv_t + (size_t)1280 * 1024; N = 256;  n0 = ((blk - 320) & 3) * 64;  k0 = ((blk - 320) >> 2) * 64; }
    else                { W = Wo; Wt = wo_t;                         N = 1024; n0 = ((blk - 384) & 15) * 64; k0 = ((blk - 384) >> 4) * 64; }

    __shared__ float Ts[64][65];
    const int c = tid & 63, rr = tid >> 6;
    #pragma unroll
    for (int i = 0; i < 16; ++i) {
        const int kk = i * 4 + rr;
        Ts[kk][c] = W[(size_t)(k0 + kk) * N + n0 + c];
    }
    __syncthreads();
    #pragma unroll
    for (int i = 0; i < 16; ++i) {
        const int nn = i * 4 + rr;
        Wt[(size_t)(n0 + nn) * 1024 + k0 + c] = (bf16)Ts[c][nn];
    }
}

// ---------------- bf16 MFMA GEMM, 512 threads (8 waves), 128x128 tile, BK=32 ----------------
// A(M,K) rm bf16, Bt(N,K) rm bf16. Wave grid 4(row)x2(col): wave tile 32x64.
// EPI=0: C fp32 plain. EPI=2: fused RoPE + QKV split epilogue (N=1536).
template<int EPI>
__global__ __launch_bounds__(512) void gemm_bt_kernel(
    const bf16* __restrict__ A, const bf16* __restrict__ Bt, float* __restrict__ C,
    const float* __restrict__ cosp, const float* __restrict__ sinp,
    bf16* __restrict__ qo, bf16* __restrict__ ko, bf16* __restrict__ vto,
    int M, int N, int K)
{
    __shared__ bf16 As[128 * 32];   // 8 KB, unpadded, row-major 128x32
    __shared__ bf16 Bs[128 * 32];
    const int m0 = blockIdx.x * 128, n0 = blockIdx.y * 128;
    const int tid = threadIdx.x;
    const int w = tid >> 6, lane = tid & 63, g = lane >> 4, li = lane & 15;
    const int wm = w >> 1, wn = w & 1;      // wave tile: rows wm*32+mi*16 (mi<2), cols wn*64+ni*16 (ni<4)

    f32x4 acc[2][4];
    const f32x4 z = {0.f, 0.f, 0.f, 0.f};
    #pragma unroll
    for (int i = 0; i < 2; ++i)
        #pragma unroll
        for (int j = 0; j < 4; ++j) acc[i][j] = z;

    // staging: 512 threads x 16 B = one full 128x32 bf16 tile per operand per iter.
    // LDS dest MUST be wave-uniform (HW writes base + lane*16B): base = As + w*512 elems.
    // Lane l of wave w lands at element w*512 + l*8 == row (w*16 + l/4), 8-elem chunk (l&3).
    const int srow = tid >> 2, schunk = (tid & 3) * 8;
    const bf16* pA = A + (size_t)(m0 + srow) * K + schunk;
    const bf16* pB = Bt + (size_t)(n0 + srow) * K + schunk;
    bf16* lA = As + (size_t)w * 512;
    bf16* lB = Bs + (size_t)w * 512;

    for (int kk = 0; kk < K; kk += 32) {
        __syncthreads();
        gl_lds16(pA + kk, lA);
        gl_lds16(pB + kk, lB);
        __syncthreads();
        bf16x8 af[2], bfr[4];
        #pragma unroll
        for (int mi = 0; mi < 2; ++mi) af[mi] = *(const bf16x8*)&As[(wm * 32 + mi * 16 + li) * 32 + g * 8];
        #pragma unroll
        for (int ni = 0; ni < 4; ++ni) bfr[ni] = *(const bf16x8*)&Bs[(wn * 64 + ni * 16 + li) * 32 + g * 8];
        #pragma unroll
        for (int mi = 0; mi < 2; ++mi)
            #pragma unroll
            for (int ni = 0; ni < 4; ++ni)
                acc[mi][ni] = __builtin_amdgcn_mfma_f32_16x16x32_bf16(af[mi], bfr[ni], acc[mi][ni], 0, 0, 0);
    }

    const int row0 = m0 + wm * 32, col0 = n0 + wn * 64;
    if (EPI == 0) {
        #pragma unroll
        for (int mi = 0; mi < 2; ++mi)
            #pragma unroll
            for (int ni = 0; ni < 4; ++ni)
                #pragma unroll
                for (int r = 0; r < 4; ++r)
                    C[(size_t)(row0 + mi * 16 + g * 4 + r) * N + col0 + ni * 16 + li] = acc[mi][ni][r];
    } else {
        // fused RoPE + split. cols: [0,1024) q, [1024,1280) k, [1280,1536) v.
        // rotate_half partner of col is col^32 == acc[mi][ni^2][r] (same wave, in-register).
        #pragma unroll
        for (int ni = 0; ni < 4; ++ni) {
            const int col = col0 + ni * 16 + li;
            const int d = col & 63;
            #pragma unroll
            for (int mi = 0; mi < 2; ++mi) {
                #pragma unroll
                for (int r = 0; r < 4; ++r) {
                    const int row = row0 + mi * 16 + g * 4 + r;
                    const int bb = row >> 11, s = row & 2047;
                    float val = acc[mi][ni][r];
                    if (col < 1280) {
                        const float pairv = acc[mi][ni ^ 2][r];
                        const float rot = (d < 32) ? -pairv : pairv;
                        val = val * cosp[s * 64 + d] + rot * sinp[s * 64 + d];
                    }
                    if (col < 1024) {
                        const int hh = col >> 6;
                        qo[(((size_t)bb * NH + hh) * SS + s) * HD + d] = (bf16)val;
                    } else if (col < 1280) {
                        const int kh = (col - 1024) >> 6;
                        ko[(((size_t)bb * NKV + kh) * SS + s) * HD + d] = (bf16)val;
                    } else {
                        const int kh = (col - 1280) >> 6;
                        vto[(((size_t)bb * NKV + kh) * HD + d) * SS + s] = (bf16)val;  // V^T: [d][s]
                    }
                }
            }
        }
    }
}

// ---------------- Flash attention v3: 128-key chunks, paired Q-tiles, no-max exp2 softmax ----------------
#define FP 72
#define FPV 136
__global__ __launch_bounds__(256) void flash_kernel(const bf16* __restrict__ q, const bf16* __restrict__ k,
                                                    const bf16* __restrict__ vt, bf16* __restrict__ o)
{
    __shared__ bf16 Ks[128][FP];     // 128 keys x 64 d
    __shared__ bf16 Vt[64][FPV];     // 64 d x 128 keys
    __shared__ bf16 Ps[4][16][FP];

    const int blk = blockIdx.x;
    const int p = blk & 15;
    const int h = (blk >> 4) & 15;
    const int b = blk >> 8;
    const int kvh = h >> 2;
    const int tid = threadIdx.x;
    const int w = tid >> 6, lane = tid & 63, g = lane >> 4, li = lane & 15;

    const bf16* qh = q + ((size_t)b * NH + h) * SS * HD;
    const bf16* kh = k + ((size_t)b * NKV + kvh) * SS * HD;
    const bf16* vh = vt + ((size_t)b * NKV + kvh) * (size_t)HD * SS;

    bf16x8 ones;
    #pragma unroll
    for (int j = 0; j < 8; ++j) ones[j] = (bf16)1.0f;
    const f32x4 z = {0.f, 0.f, 0.f, 0.f};

    #pragma unroll
    for (int phase = 0; phase < 2; ++phase) {
        const int qt = phase ? p : (31 - p);

        // Q fragments straight from global (A-layout: row=li, k=g*8+j)
        const bf16* qrow = qh + (size_t)(qt * 64 + w * 16 + li) * HD;
        bf16x8 qf[2];
        qf[0] = *(const bf16x8*)(qrow + g * 8);
        qf[1] = *(const bf16x8*)(qrow + 32 + g * 8);

        f32x4 o_acc[4], l_acc;
        #pragma unroll
        for (int nt = 0; nt < 4; ++nt) o_acc[nt] = z;
        l_acc = z;

        for (int kt0 = 0; kt0 <= qt; kt0 += 2) {
            __syncthreads();
            {   // stage 128 keys of K (rows=key, 2 thr/row x 32 elems) and V^T (rows=d, 4 thr/row x 32 elems)
                const int krow = tid >> 1, kcol = (tid & 1) * 32;
                const uint4* ks = (const uint4*)(kh + (size_t)(kt0 * 64 + krow) * HD + kcol);
                const uint4 a0 = ks[0], a1 = ks[1], a2 = ks[2], a3 = ks[3];
                *(uint4*)&Ks[krow][kcol]      = a0;
                *(uint4*)&Ks[krow][kcol + 8]  = a1;
                *(uint4*)&Ks[krow][kcol + 16] = a2;
                *(uint4*)&Ks[krow][kcol + 24] = a3;
                const int vrow = tid >> 2, vcol = (tid & 3) * 32;
                const uint4* vs = (const uint4*)(vh + (size_t)vrow * SS + kt0 * 64 + vcol);
                const uint4 c0 = vs[0], c1 = vs[1], c2 = vs[2], c3 = vs[3];
                *(uint4*)&Vt[vrow][vcol]      = c0;
                *(uint4*)&Vt[vrow][vcol + 8]  = c1;
                *(uint4*)&Vt[vrow][vcol + 16] = c2;
                *(uint4*)&Vt[vrow][vcol + 24] = c3;
            }
            __syncthreads();

            #pragma unroll
            for (int sub = 0; sub < 2; ++sub) {
                const int kt = kt0 + sub;
                if (kt > qt) break;

                // S = Q @ K^T  (16 q-rows x 64 keys per wave)
                f32x4 s_acc[4];
                #pragma unroll
                for (int nt = 0; nt < 4; ++nt) s_acc[nt] = z;
                #pragma unroll
                for (int t = 0; t < 2; ++t)
                    #pragma unroll
                    for (int nt = 0; nt < 4; ++nt) {
                        const bf16x8 kf = *(const bf16x8*)&Ks[sub * 64 + nt * 16 + li][t * 32 + g * 8];
                        s_acc[nt] = __builtin_amdgcn_mfma_f32_16x16x32_bf16(qf[t], kf, s_acc[nt], 0, 0, 0);
                    }

                // scale (exp2-folded), causal mask on diagonal, exp2, P -> LDS (bf16)
                const bool diag = (kt == qt);
                const int qr0 = qt * 64 + w * 16 + g * 4;
                #pragma unroll
                for (int nt = 0; nt < 4; ++nt) {
                    const int key = kt * 64 + nt * 16 + li;
                    #pragma unroll
                    for (int r = 0; r < 4; ++r) {
                        float sv = s_acc[nt][r] * SM_SCALE;
                        if (diag && key > qr0 + r) sv = -1e30f;
                        Ps[w][g * 4 + r][nt * 16 + li] = (bf16)exp2f(sv);
                    }
                }
                // same-wave LDS round-trip (C-layout -> A-layout); no barrier needed

                // O += P @ V ; l += P @ 1 (rowsum via ones-MFMA, broadcast to all lanes)
                #pragma unroll
                for (int t = 0; t < 2; ++t) {
                    const bf16x8 pf = *(const bf16x8*)&Ps[w][li][t * 32 + g * 8];
                    l_acc = __builtin_amdgcn_mfma_f32_16x16x32_bf16(pf, ones, l_acc, 0, 0, 0);
                    #pragma unroll
                    for (int nt = 0; nt < 4; ++nt) {
                        const bf16x8 vf = *(const bf16x8*)&Vt[nt * 16 + li][sub * 64 + t * 32 + g * 8];
                        o_acc[nt] = __builtin_amdgcn_mfma_f32_16x16x32_bf16(pf, vf, o_acc[nt], 0, 0, 0);
                    }
                }
            }
        }

        // epilogue: O / l -> (b, s, h, d) bf16
        #pragma unroll
        for (int r = 0; r < 4; ++r) {
            const float inv = 1.f / l_acc[r];
            const int s = qt * 64 + w * 16 + g * 4 + r;
            bf16* orow = o + (((size_t)b * SS + s) * NH + h) * HD;
            #pragma unroll
            for (int nt = 0; nt < 4; ++nt) orow[nt * 16 + li] = (bf16)(o_acc[nt][r] * inv);
        }
    }
}

extern "C" void kernel_launch(void* const* d_in, const int* in_sizes, int n_in,
                              void* d_out, int out_size, void* d_ws, size_t ws_size,
                              hipStream_t stream) {
    const float* x     = (const float*)d_in[0];
    const float* cos_t = (const float*)d_in[1];
    const float* sin_t = (const float*)d_in[2];
    const float* Wq    = (const float*)d_in[3];
    const float* Wk    = (const float*)d_in[4];
    const float* Wv    = (const float*)d_in[5];
    const float* Wo    = (const float*)d_in[6];
    float* out = (float*)d_out;

    char* wsb = (char*)d_ws;
    bf16* x_b    = (bf16*)(wsb);                 //  8,388,608 B (aliased as o_b after QKV GEMM)
    bf16* wqkv_t = (bf16*)(wsb + 8388608);       //  3,145,728 B (1536 x 1024)
    bf16* wo_t   = (bf16*)(wsb + 11534336);      //  2,097,152 B (1024 x 1024)
    bf16* q_b    = (bf16*)(wsb + 13631488);      //  8,388,608 B
    bf16* k_b    = (bf16*)(wsb + 22020096);      //  2,097,152 B
    bf16* vt_b   = (bf16*)(wsb + 24117248);      //  2,097,152 B -> total 26,214,400 B
    bf16* o_b    = x_b;

    prep_kernel<<<1152, 256, 0, stream>>>(x, Wq, Wk, Wv, Wo, x_b, wqkv_t, wo_t);

    // QKV GEMM with fused RoPE + split (writes q_b, k_b, vt_b directly)
    gemm_bt_kernel<2><<<dim3(32, 12), 512, 0, stream>>>(x_b, wqkv_t, nullptr, cos_t, sin_t,
                                                        q_b, k_b, vt_b, 4096, 1536, 1024);
    flash_kernel<<<512, 256, 0, stream>>>(q_b, k_b, vt_b, o_b);
    gemm_bt_kernel<0><<<dim3(32, 8), 512, 0, stream>>>(o_b, wo_t, out, nullptr, nullptr,
                                                       nullptr, nullptr, nullptr, 4096, 1024, 1024);
}

// Round 7
// 179.616 us; speedup vs baseline: 26.2082x; 1.0728x over previous
//
#include <hip/hip_runtime.h>

#define SS 2048
#define NH 16
#define NKV 4
#define HD 64

typedef __bf16 bf16;
typedef __bf16 bf16x8 __attribute__((ext_vector_type(8)));
typedef float f32x4 __attribute__((ext_vector_type(4)));

// softmax scale folded into Q at the QKV epilogue: (1/sqrt(64)) * log2(e)
#define SM_SCALE 0.18033688011f

__device__ __forceinline__ void gl_lds16(const bf16* g, bf16* l) {
    __builtin_amdgcn_global_load_lds((const __attribute__((address_space(1))) void*)g,
                                     (__attribute__((address_space(3))) void*)l, 16, 0, 0);
}

// ---------------- prep: convert x to bf16 + transpose/convert all weights ----------------
// blocks 0..255: Wq (16x16 64-tiles), 256..319: Wk, 320..383: Wv, 384..639: Wo,
// 640..1151: x fp32->bf16 (512 blocks x 256 thr x 8 float4 = 1,048,576 float4 = whole x).
__global__ __launch_bounds__(256) void prep_kernel(
    const float* __restrict__ x, const float* __restrict__ Wq, const float* __restrict__ Wk,
    const float* __restrict__ Wv, const float* __restrict__ Wo,
    bf16* __restrict__ xb, bf16* __restrict__ wqkv_t, bf16* __restrict__ wo_t)
{
    const int blk = blockIdx.x;
    const int tid = threadIdx.x;
    if (blk >= 640) {
        const float4* xv = (const float4*)x;
        const size_t base = (size_t)(blk - 640) * 2048 + tid;   // float4 units
        #pragma unroll
        for (int j = 0; j < 8; ++j) {
            const float4 v = xv[base + j * 256];
            bf16* o = xb + (base + j * 256) * 4;
            o[0] = (bf16)v.x; o[1] = (bf16)v.y; o[2] = (bf16)v.z; o[3] = (bf16)v.w;
        }
        return;
    }
    const float* W; bf16* Wt; int N, n0, k0;
    if (blk < 256)      { W = Wq; Wt = wqkv_t;                       N = 1024; n0 = (blk & 15) * 64;         k0 = (blk >> 4) * 64; }
    else if (blk < 320) { W = Wk; Wt = wqkv_t + (size_t)1024 * 1024; N = 256;  n0 = ((blk - 256) & 3) * 64;  k0 = ((blk - 256) >> 2) * 64; }
    else if (blk < 384) { W = Wv; Wt = wqkv_t + (size_t)1280 * 1024; N = 256;  n0 = ((blk - 320) & 3) * 64;  k0 = ((blk - 320) >> 2) * 64; }
    else                { W = Wo; Wt = wo_t;                         N = 1024; n0 = ((blk - 384) & 15) * 64; k0 = ((blk - 384) >> 4) * 64; }

    __shared__ float Ts[64][65];
    const int c = tid & 63, rr = tid >> 6;
    #pragma unroll
    for (int i = 0; i < 16; ++i) {
        const int kk = i * 4 + rr;
        Ts[kk][c] = W[(size_t)(k0 + kk) * N + n0 + c];
    }
    __syncthreads();
    #pragma unroll
    for (int i = 0; i < 16; ++i) {
        const int nn = i * 4 + rr;
        Wt[(size_t)(n0 + nn) * 1024 + k0 + c] = (bf16)Ts[c][nn];
    }
}

// ---------------- bf16 MFMA GEMM, 512 threads (8 waves), 128x128 tile, BK=64 ----------------
// A(M,K) rm bf16, Bt(N,K) rm bf16. Wave grid 4(row)x2(col): wave tile 32x64.
// Staging via global_load_lds (wave-uniform dest) with chunk-XOR swizzle:
//   physical chunk p of row r holds logical k-chunk p ^ (r&7)  -> conflict-free frag reads.
// EPI=0: C fp32 plain. EPI=2: fused RoPE + QKV split epilogue (N=1536), Q pre-scaled by SM_SCALE.
template<int EPI>
__global__ __launch_bounds__(512) void gemm_bt_kernel(
    const bf16* __restrict__ A, const bf16* __restrict__ Bt, float* __restrict__ C,
    const float* __restrict__ cosp, const float* __restrict__ sinp,
    bf16* __restrict__ qo, bf16* __restrict__ ko, bf16* __restrict__ vto,
    int M, int N, int K)
{
    __shared__ bf16 As[128 * 64];   // 16 KB, unpadded 128x64, chunk-swizzled
    __shared__ bf16 Bs[128 * 64];
    const int m0 = blockIdx.x * 128, n0 = blockIdx.y * 128;
    const int tid = threadIdx.x;
    const int w = tid >> 6, lane = tid & 63, g = lane >> 4, li = lane & 15;
    const int wm = w >> 1, wn = w & 1;      // wave tile: rows wm*32+mi*16 (mi<2), cols wn*64+ni*16 (ni<4)

    f32x4 acc[2][4];
    const f32x4 z = {0.f, 0.f, 0.f, 0.f};
    #pragma unroll
    for (int i = 0; i < 2; ++i)
        #pragma unroll
        for (int j = 0; j < 4; ++j) acc[i][j] = z;

    // staging: 2 calls per operand; call c covers rows c*64..c*64+63.
    // thread t -> row c*64 + (t>>3), fetches global chunk ((t&7) ^ (row&7)) (swizzle).
    const int srow = tid >> 3;                         // 0..63
    const int schunk = ((tid & 7) ^ (srow & 7)) * 8;   // swizzled 8-elem chunk
    const bf16* pA0 = A + (size_t)(m0 + srow) * K + schunk;
    const bf16* pA1 = A + (size_t)(m0 + 64 + srow) * K + schunk;
    const bf16* pB0 = Bt + (size_t)(n0 + srow) * K + schunk;
    const bf16* pB1 = Bt + (size_t)(n0 + 64 + srow) * K + schunk;
    bf16* lA0 = As + (size_t)w * 512;           // wave-uniform dests
    bf16* lA1 = As + 4096 + (size_t)w * 512;
    bf16* lB0 = Bs + (size_t)w * 512;
    bf16* lB1 = Bs + 4096 + (size_t)w * 512;

    for (int kk = 0; kk < K; kk += 64) {
        __syncthreads();
        gl_lds16(pA0 + kk, lA0);
        gl_lds16(pA1 + kk, lA1);
        gl_lds16(pB0 + kk, lB0);
        gl_lds16(pB1 + kk, lB1);
        __syncthreads();
        #pragma unroll
        for (int t = 0; t < 2; ++t) {
            bf16x8 af[2], bfr[4];
            #pragma unroll
            for (int mi = 0; mi < 2; ++mi) {
                const int row = wm * 32 + mi * 16 + li;
                af[mi] = *(const bf16x8*)&As[row * 64 + (((t * 4 + g) ^ (li & 7)) * 8)];
            }
            #pragma unroll
            for (int ni = 0; ni < 4; ++ni) {
                const int row = wn * 64 + ni * 16 + li;
                bfr[ni] = *(const bf16x8*)&Bs[row * 64 + (((t * 4 + g) ^ (li & 7)) * 8)];
            }
            #pragma unroll
            for (int mi = 0; mi < 2; ++mi)
                #pragma unroll
                for (int ni = 0; ni < 4; ++ni)
                    acc[mi][ni] = __builtin_amdgcn_mfma_f32_16x16x32_bf16(af[mi], bfr[ni], acc[mi][ni], 0, 0, 0);
        }
    }

    const int row0 = m0 + wm * 32, col0 = n0 + wn * 64;
    if (EPI == 0) {
        #pragma unroll
        for (int mi = 0; mi < 2; ++mi)
            #pragma unroll
            for (int ni = 0; ni < 4; ++ni)
                #pragma unroll
                for (int r = 0; r < 4; ++r)
                    C[(size_t)(row0 + mi * 16 + g * 4 + r) * N + col0 + ni * 16 + li] = acc[mi][ni][r];
    } else {
        // fused RoPE + split. cols: [0,1024) q (pre-scaled by SM_SCALE), [1024,1280) k, [1280,1536) v.
        // rotate_half partner of col is col^32 == acc[mi][ni^2][r] (same wave, in-register).
        #pragma unroll
        for (int ni = 0; ni < 4; ++ni) {
            const int col = col0 + ni * 16 + li;
            const int d = col & 63;
            #pragma unroll
            for (int mi = 0; mi < 2; ++mi) {
                #pragma unroll
                for (int r = 0; r < 4; ++r) {
                    const int row = row0 + mi * 16 + g * 4 + r;
                    const int bb = row >> 11, s = row & 2047;
                    float val = acc[mi][ni][r];
                    if (col < 1280) {
                        const float pairv = acc[mi][ni ^ 2][r];
                        const float rot = (d < 32) ? -pairv : pairv;
                        val = val * cosp[s * 64 + d] + rot * sinp[s * 64 + d];
                    }
                    if (col < 1024) {
                        const int hh = col >> 6;
                        qo[(((size_t)bb * NH + hh) * SS + s) * HD + d] = (bf16)(val * SM_SCALE);
                    } else if (col < 1280) {
                        const int kh = (col - 1024) >> 6;
                        ko[(((size_t)bb * NKV + kh) * SS + s) * HD + d] = (bf16)val;
                    } else {
                        const int kh = (col - 1280) >> 6;
                        vto[(((size_t)bb * NKV + kh) * HD + d) * SS + s] = (bf16)val;  // V^T: [d][s]
                    }
                }
            }
        }
    }
}

// ---------------- Flash attention v4: swizzled P, diag split, pre-scaled Q ----------------
#define FP 72
#define FPV 136
__global__ __launch_bounds__(256) void flash_kernel(const bf16* __restrict__ q, const bf16* __restrict__ k,
                                                    const bf16* __restrict__ vt, bf16* __restrict__ o)
{
    __shared__ bf16 Ks[128][FP];     // 128 keys x 64 d
    __shared__ bf16 Vt[64][FPV];     // 64 d x 128 keys
    __shared__ bf16 Ps[4][16][FP];   // per-wave P, column-XOR-swizzled by g

    const int blk = blockIdx.x;
    const int p = blk & 15;
    const int h = (blk >> 4) & 15;
    const int b = blk >> 8;
    const int kvh = h >> 2;
    const int tid = threadIdx.x;
    const int w = tid >> 6, lane = tid & 63, g = lane >> 4, li = lane & 15;

    const bf16* qh = q + ((size_t)b * NH + h) * SS * HD;
    const bf16* kh = k + ((size_t)b * NKV + kvh) * SS * HD;
    const bf16* vh = vt + ((size_t)b * NKV + kvh) * (size_t)HD * SS;

    bf16x8 ones;
    #pragma unroll
    for (int j = 0; j < 8; ++j) ones[j] = (bf16)1.0f;
    const f32x4 z = {0.f, 0.f, 0.f, 0.f};

    #pragma unroll
    for (int phase = 0; phase < 2; ++phase) {
        const int qt = phase ? p : (31 - p);

        // Q fragments straight from global (A-layout: row=li, k=g*8+j); Q pre-scaled.
        const bf16* qrow = qh + (size_t)(qt * 64 + w * 16 + li) * HD;
        bf16x8 qf[2];
        qf[0] = *(const bf16x8*)(qrow + g * 8);
        qf[1] = *(const bf16x8*)(qrow + 32 + g * 8);

        f32x4 o_acc[4], l_acc;
        #pragma unroll
        for (int nt = 0; nt < 4; ++nt) o_acc[nt] = z;
        l_acc = z;

        for (int kt0 = 0; kt0 <= qt; kt0 += 2) {
            __syncthreads();
            {   // stage 128 keys of K (rows=key, 2 thr/row x 32 elems) and V^T (rows=d, 4 thr/row x 32 elems)
                const int krow = tid >> 1, kcol = (tid & 1) * 32;
                const uint4* ks = (const uint4*)(kh + (size_t)(kt0 * 64 + krow) * HD + kcol);
                const uint4 a0 = ks[0], a1 = ks[1], a2 = ks[2], a3 = ks[3];
                *(uint4*)&Ks[krow][kcol]      = a0;
                *(uint4*)&Ks[krow][kcol + 8]  = a1;
                *(uint4*)&Ks[krow][kcol + 16] = a2;
                *(uint4*)&Ks[krow][kcol + 24] = a3;
                const int vrow = tid >> 2, vcol = (tid & 3) * 32;
                const uint4* vs = (const uint4*)(vh + (size_t)vrow * SS + kt0 * 64 + vcol);
                const uint4 c0 = vs[0], c1 = vs[1], c2 = vs[2], c3 = vs[3];
                *(uint4*)&Vt[vrow][vcol]      = c0;
                *(uint4*)&Vt[vrow][vcol + 8]  = c1;
                *(uint4*)&Vt[vrow][vcol + 16] = c2;
                *(uint4*)&Vt[vrow][vcol + 24] = c3;
            }
            __syncthreads();

            #pragma unroll
            for (int sub = 0; sub < 2; ++sub) {
                const int kt = kt0 + sub;
                if (kt > qt) break;

                // S = Q @ K^T  (16 q-rows x 64 keys per wave); scores arrive pre-scaled
                f32x4 s_acc[4];
                #pragma unroll
                for (int nt = 0; nt < 4; ++nt) s_acc[nt] = z;
                #pragma unroll
                for (int t = 0; t < 2; ++t)
                    #pragma unroll
                    for (int nt = 0; nt < 4; ++nt) {
                        const bf16x8 kf = *(const bf16x8*)&Ks[sub * 64 + nt * 16 + li][t * 32 + g * 8];
                        s_acc[nt] = __builtin_amdgcn_mfma_f32_16x16x32_bf16(qf[t], kf, s_acc[nt], 0, 0, 0);
                    }

                // exp2 + P -> LDS (bf16), column swizzled by g. Diag tile masked separately.
                if (kt == qt) {
                    const int qr0 = qt * 64 + w * 16 + g * 4;
                    #pragma unroll
                    for (int nt = 0; nt < 4; ++nt) {
                        const int key = kt * 64 + nt * 16 + li;
                        #pragma unroll
                        for (int r = 0; r < 4; ++r) {
                            float sv = s_acc[nt][r];
                            if (key > qr0 + r) sv = -1e30f;
                            Ps[w][g * 4 + r][(nt * 16 + li) ^ (g * 16)] = (bf16)exp2f(sv);
                        }
                    }
                } else {
                    #pragma unroll
                    for (int nt = 0; nt < 4; ++nt)
                        #pragma unroll
                        for (int r = 0; r < 4; ++r)
                            Ps[w][g * 4 + r][(nt * 16 + li) ^ (g * 16)] = (bf16)exp2f(s_acc[nt][r]);
                }
                // same-wave LDS round-trip (C-layout -> A-layout); no barrier needed

                // O += P @ V ; l += P @ 1 (rowsum via ones-MFMA)
                #pragma unroll
                for (int t = 0; t < 2; ++t) {
                    const bf16x8 pf = *(const bf16x8*)&Ps[w][li][(t * 32 + g * 8) ^ ((li >> 2) * 16)];
                    l_acc = __builtin_amdgcn_mfma_f32_16x16x32_bf16(pf, ones, l_acc, 0, 0, 0);
                    #pragma unroll
                    for (int nt = 0; nt < 4; ++nt) {
                        const bf16x8 vf = *(const bf16x8*)&Vt[nt * 16 + li][sub * 64 + t * 32 + g * 8];
                        o_acc[nt] = __builtin_amdgcn_mfma_f32_16x16x32_bf16(pf, vf, o_acc[nt], 0, 0, 0);
                    }
                }
            }
        }

        // epilogue: O / l -> (b, s, h, d) bf16
        #pragma unroll
        for (int r = 0; r < 4; ++r) {
            const float inv = 1.f / l_acc[r];
            const int s = qt * 64 + w * 16 + g * 4 + r;
            bf16* orow = o + (((size_t)b * SS + s) * NH + h) * HD;
            #pragma unroll
            for (int nt = 0; nt < 4; ++nt) orow[nt * 16 + li] = (bf16)(o_acc[nt][r] * inv);
        }
    }
}

extern "C" void kernel_launch(void* const* d_in, const int* in_sizes, int n_in,
                              void* d_out, int out_size, void* d_ws, size_t ws_size,
                              hipStream_t stream) {
    const float* x     = (const float*)d_in[0];
    const float* cos_t = (const float*)d_in[1];
    const float* sin_t = (const float*)d_in[2];
    const float* Wq    = (const float*)d_in[3];
    const float* Wk    = (const float*)d_in[4];
    const float* Wv    = (const float*)d_in[5];
    const float* Wo    = (const float*)d_in[6];
    float* out = (float*)d_out;

    char* wsb = (char*)d_ws;
    bf16* x_b    = (bf16*)(wsb);                 //  8,388,608 B (aliased as o_b after QKV GEMM)
    bf16* wqkv_t = (bf16*)(wsb + 8388608);       //  3,145,728 B (1536 x 1024)
    bf16* wo_t   = (bf16*)(wsb + 11534336);      //  2,097,152 B (1024 x 1024)
    bf16* q_b    = (bf16*)(wsb + 13631488);      //  8,388,608 B
    bf16* k_b    = (bf16*)(wsb + 22020096);      //  2,097,152 B
    bf16* vt_b   = (bf16*)(wsb + 24117248);      //  2,097,152 B -> total 26,214,400 B
    bf16* o_b    = x_b;

    prep_kernel<<<1152, 256, 0, stream>>>(x, Wq, Wk, Wv, Wo, x_b, wqkv_t, wo_t);

    // QKV GEMM with fused RoPE + split (writes q_b pre-scaled, k_b, vt_b directly)
    gemm_bt_kernel<2><<<dim3(32, 12), 512, 0, stream>>>(x_b, wqkv_t, nullptr, cos_t, sin_t,
                                                        q_b, k_b, vt_b, 4096, 1536, 1024);
    flash_kernel<<<512, 256, 0, stream>>>(q_b, k_b, vt_b, o_b);
    gemm_bt_kernel<0><<<dim3(32, 8), 512, 0, stream>>>(o_b, wo_t, out, nullptr, nullptr,
                                                       nullptr, nullptr, nullptr, 4096, 1024, 1024);
}